// Round 3
// baseline (592.732 us; speedup 1.0000x reference)
//
#include <hip/hip_runtime.h>

#define HDIM 768

constexpr int KC    = 16;           // k-columns per K-half staged per chunk
constexpr int KHALF = HDIM / 2;     // 384
constexpr int NCH   = KHALF / KC;   // 24 chunks
constexpr int RPB   = 128;          // rows per block
// LDS: x double-buffer, slot-major: [buf][slot(8)][row(128)] float4 -> conflict-free,
// linear dest for global_load_lds. W double-buffer: [buf][head(17)][slot(8)] float4.

// global_load_lds: 16B per lane, dest = wave-uniform lds base + lane*16 (implicit).
__device__ __forceinline__ void gload_lds16(const float* g, float* l) {
    __builtin_amdgcn_global_load_lds(
        (const __attribute__((address_space(1))) unsigned int*)(g),
        (__attribute__((address_space(3))) unsigned int*)(l), 16, 0, 0);
}

// head j -> (weight array, row). Order FIXED: accumulation order must match
// previous rounds exactly (head-major, then x,y,z,w).
#define W_LIST(OP)                                                            \
    OP(0,  Wa,  0) OP(1,  Wa,  1)                                             \
    OP(2,  Wb,  0) OP(3,  Wb,  1) OP(4,  Wb,  2) OP(5,  Wb,  3)               \
    OP(6,  Wc1, 0) OP(7,  Wc1, 1)                                             \
    OP(8,  Wc2, 0) OP(9,  Wc2, 1) OP(10, Wc2, 2)                              \
    OP(11, Wc3, 0) OP(12, Wc3, 1) OP(13, Wc3, 2) OP(14, Wc3, 3)               \
    OP(15, Wc4, 0) OP(16, Wc4, 1)

// W broadcast read from LDS slice: head j at float offset j*32, slot q at +q*4.
#define LOADW(j, WP, R) const float4 w##j = *(const float4*)(wb + (j) * 32);

#define FMAW(j, WP, R)                                                        \
    ac0[j] = fmaf(xv0.x, w##j.x, ac0[j]); ac1[j] = fmaf(xv1.x, w##j.x, ac1[j]); \
    ac0[j] = fmaf(xv0.y, w##j.y, ac0[j]); ac1[j] = fmaf(xv1.y, w##j.y, ac1[j]); \
    ac0[j] = fmaf(xv0.z, w##j.z, ac0[j]); ac1[j] = fmaf(xv1.z, w##j.z, ac1[j]); \
    ac0[j] = fmaf(xv0.w, w##j.w, ac0[j]); ac1[j] = fmaf(xv1.w, w##j.w, ac1[j]);

// Epilogue for one row given its 17 fp32-exact head accumulators.
#define WRITE_ROW(ACC, ROW)                                                   \
    do {                                                                      \
        const int row_ = (ROW);                                               \
        if (row_ < B) {                                                       \
            const float oa0 = ACC[0] + ba[0];                                 \
            const float oa1 = ACC[1] + ba[1];                                 \
            const bool active = oa1 > oa0;                                    \
            const float tb0 = ACC[2] + bb[0];                                 \
            const float tb1 = ACC[3] + bb[1];                                 \
            const float tb2 = ACC[4] + bb[2];                                 \
            const float tb3 = ACC[5] + bb[3];                                 \
            int   p = 0;                                                      \
            float m = tb0;                                                    \
            if (tb1 > m) { m = tb1; p = 1; }                                  \
            if (tb2 > m) { m = tb2; p = 2; }                                  \
            if (tb3 > m) { m = tb3; p = 3; }                                  \
            float* oa = out + (size_t)2 * row_;                               \
            oa[0] = oa0;                                                      \
            oa[1] = oa1;                                                      \
            float* ob = out + (size_t)2 * B + (size_t)5 * row_;               \
            ob[0] = 0.f;                                                      \
            ob[1] = active ? tb0 : 0.f;                                       \
            ob[2] = active ? tb1 : 0.f;                                       \
            ob[3] = active ? tb2 : 0.f;                                       \
            ob[4] = active ? tb3 : 0.f;                                       \
            const bool m0 = active && (p == 0);                               \
            const bool m1 = active && (p == 1);                               \
            const bool m2 = active && (p == 2);                               \
            const bool m3 = active && (p == 3);                               \
            float* oc = out + (size_t)7 * B + (size_t)11 * row_;              \
            oc[0]  = m0 ? ACC[6]  + bc1[0] : 0.f;                             \
            oc[1]  = m0 ? ACC[7]  + bc1[1] : 0.f;                             \
            oc[2]  = m1 ? ACC[8]  + bc2[0] : 0.f;                             \
            oc[3]  = m1 ? ACC[9]  + bc2[1] : 0.f;                             \
            oc[4]  = m1 ? ACC[10] + bc2[2] : 0.f;                             \
            oc[5]  = m2 ? ACC[11] + bc3[0] : 0.f;                             \
            oc[6]  = m2 ? ACC[12] + bc3[1] : 0.f;                             \
            oc[7]  = m2 ? ACC[13] + bc3[2] : 0.f;                             \
            oc[8]  = m2 ? ACC[14] + bc3[3] : 0.f;                             \
            oc[9]  = m3 ? ACC[15] + bc4[0] : 0.f;                             \
            oc[10] = m3 ? ACC[16] + bc4[1] : 0.f;                             \
        }                                                                     \
    } while (0)

__global__ __launch_bounds__(128, 2)
void hier_fused(const float* __restrict__ x,
                const float* __restrict__ Wa,  const float* __restrict__ ba,
                const float* __restrict__ Wb,  const float* __restrict__ bb,
                const float* __restrict__ Wc1, const float* __restrict__ bc1,
                const float* __restrict__ Wc2, const float* __restrict__ bc2,
                const float* __restrict__ Wc3, const float* __restrict__ bc3,
                const float* __restrict__ Wc4, const float* __restrict__ bc4,
                float* __restrict__ out, int B)
{
    __shared__ float xs[2][8 * 512];    // 2 x 16 KiB: [slot][row] float4, slot-major
    __shared__ float ws[2][544];        // 2 x 2176 B: [head][slot] float4

    const int t       = threadIdx.x;    // 0..127
    const int rr      = t & 63;         // first row of this thread's 2-row tile
    const int kh      = t >> 6;         // K-half: 0 -> k[0,384), 1 -> k[384,768)
    const int wv      = t >> 6;         // wave id (uniform within wave)
    const int rowBase = blockIdx.x * RPB;

    float ac0[17], ac1[17];             // rows rr and rr+64
#pragma unroll
    for (int j = 0; j < 17; ++j) { ac0[j] = 0.f; ac1[j] = 0.f; }

    // ---- per-lane staging source addresses (precomputed once) ----
    // x: lane t stages row rowBase+t; call j covers x-slot j (j<4: half0, j>=4: half1)
    int srow = rowBase + t; if (srow >= B) srow = B - 1;
    const float* xsrc = x + (size_t)srow * HDIM;

    // W call 1: item t -> head h=t>>3, slot s=t&7 (heads 0..15)
    const float* wsrc1;
    {
        const int h = t >> 3, s = t & 7;
        const float* base =
            h < 2  ? Wa  + (size_t)h * HDIM :
            h < 6  ? Wb  + (size_t)(h - 2) * HDIM :
            h < 8  ? Wc1 + (size_t)(h - 6) * HDIM :
            h < 11 ? Wc2 + (size_t)(h - 8) * HDIM :
            h < 15 ? Wc3 + (size_t)(h - 11) * HDIM :
                     Wc4 + (size_t)(h - 15) * HDIM;
        wsrc1 = base + (s < 4 ? s * 4 : KHALF + (s - 4) * 4);
    }
    // W call 2: head 16 (= Wc4 row 1), slot t (only lanes t<8 active)
    const int s2 = t & 7;
    const float* wsrc2 = Wc4 + HDIM + (s2 < 4 ? s2 * 4 : KHALF + (s2 - 4) * 4);

    // ---- stage one chunk (x: 8 calls, W: 2 calls) into buffer (cc&1) ----
#define STAGE(cc)                                                             \
    do {                                                                      \
        const int nb_  = (cc) & 1;                                            \
        const int coff = (cc) * KC;      /* column advance per chunk (floats) */ \
        _Pragma("unroll")                                                     \
        for (int j = 0; j < 8; ++j) {                                         \
            const int go = (j < 4 ? j * 4 : KHALF + (j - 4) * 4) + coff;      \
            gload_lds16(xsrc + go, &xs[nb_][j * 512 + wv * 256]);             \
        }                                                                     \
        gload_lds16(wsrc1 + coff, &ws[nb_][wv * 256]);                        \
        if (t < 8) gload_lds16(wsrc2 + coff, &ws[nb_][512]);                  \
    } while (0)

    STAGE(0);
    __syncthreads();                    // chunk 0 resident

    for (int c = 0; c < NCH; ++c) {
        if (c + 1 < NCH) STAGE(c + 1);  // vmcnt-only prefetch, overlaps compute below

        const int cur = c & 1;
        const float* xbase = &xs[cur][kh * 4 * 512 + rr * 4];
#pragma unroll
        for (int q = 0; q < 4; ++q) {   // kk = 4*q, k ascending -> exact acc order
            const float4 xv0 = *(const float4*)(xbase + q * 512);
            const float4 xv1 = *(const float4*)(xbase + q * 512 + 256);
            const float* wb  = &ws[cur][kh * 16 + q * 4];
            W_LIST(LOADW)               // 17 broadcast ds_read_b128 (lgkmcnt only)
            W_LIST(FMAW)                // 136 FMAs, bit-identical order
        }
        __syncthreads();                // drains vmcnt (staging) + lgkmcnt, swap ok
    }
#undef STAGE

    // combine the two K-half partials through LDS (xs is dead now)
    if (kh == 1) {
#pragma unroll
        for (int j = 0; j < 17; ++j) {
            xs[0][rr * 18 + j]        = ac0[j];
            xs[0][(rr + 64) * 18 + j] = ac1[j];
        }
    }
    __syncthreads();
    if (kh != 0) return;

#pragma unroll
    for (int j = 0; j < 17; ++j) {
        ac0[j] += xs[0][rr * 18 + j];
        ac1[j] += xs[0][(rr + 64) * 18 + j];
    }

    WRITE_ROW(ac0, rowBase + rr);
    WRITE_ROW(ac1, rowBase + rr + 64);
}

extern "C" void kernel_launch(void* const* d_in, const int* in_sizes, int n_in,
                              void* d_out, int out_size, void* d_ws, size_t ws_size,
                              hipStream_t stream) {
    const float* x   = (const float*)d_in[0];
    const float* Wa  = (const float*)d_in[1];
    const float* ba  = (const float*)d_in[2];
    const float* Wb  = (const float*)d_in[3];
    const float* bb  = (const float*)d_in[4];
    const float* Wc1 = (const float*)d_in[5];
    const float* bc1 = (const float*)d_in[6];
    const float* Wc2 = (const float*)d_in[7];
    const float* bc2 = (const float*)d_in[8];
    const float* Wc3 = (const float*)d_in[9];
    const float* bc3 = (const float*)d_in[10];
    const float* Wc4 = (const float*)d_in[11];
    const float* bc4 = (const float*)d_in[12];

    const int B  = in_sizes[0] / HDIM;
    const int nb = (B + RPB - 1) / RPB;

    hipLaunchKernelGGL(hier_fused, dim3(nb), dim3(128), 0, stream,
                       x, Wa, ba, Wb, bb, Wc1, bc1, Wc2, bc2, Wc3, bc3, Wc4, bc4,
                       (float*)d_out, B);
}